// Round 8
// baseline (149.401 us; speedup 1.0000x reference)
//
#include <hip/hip_runtime.h>

#define Nn 2048
#define FIN 512
#define FO 64
#define SHIFT 20.0f
#define CHK 128

typedef __attribute__((ext_vector_type(8))) short bf16x8;
typedef __attribute__((ext_vector_type(4))) float f32x4;

__device__ __forceinline__ unsigned rne_bf16(float x) {   // low 16 bits = bf16(x), RNE
    unsigned u = __float_as_uint(x);
    return (u + 0x7FFFu + ((u >> 16) & 1u)) >> 16;
}
__device__ __forceinline__ float bf16_f32(unsigned s) { return __uint_as_float(s << 16); }

// ---------------- K1: h = x @ W (proven) ----------------
__global__ __launch_bounds__(256) void gat_xw(const float* __restrict__ x,
                                              const float* __restrict__ W,
                                              float* __restrict__ h) {
    __shared__ float part[2][2][FO];
    const int wave = threadIdx.x >> 6;
    const int lane = threadIdx.x & 63;
    const int rs = wave >> 1;
    const int kh = wave & 1;
    int row = blockIdx.x * 2 + rs;
    row = __builtin_amdgcn_readfirstlane(row);
    const float* xr = x + (size_t)row * FIN + kh * (FIN / 2);
    const float* Wp = W + (size_t)kh * (FIN / 2) * FO;
    float acc = 0.f;
#pragma unroll 2
    for (int k = 0; k < FIN / 2; k += 8) {
        float4 xa = *(const float4*)(xr + k);
        float4 xb = *(const float4*)(xr + k + 4);
        acc = fmaf(xa.x, Wp[(k + 0) * FO + lane], acc);
        acc = fmaf(xa.y, Wp[(k + 1) * FO + lane], acc);
        acc = fmaf(xa.z, Wp[(k + 2) * FO + lane], acc);
        acc = fmaf(xa.w, Wp[(k + 3) * FO + lane], acc);
        acc = fmaf(xb.x, Wp[(k + 4) * FO + lane], acc);
        acc = fmaf(xb.y, Wp[(k + 5) * FO + lane], acc);
        acc = fmaf(xb.z, Wp[(k + 6) * FO + lane], acc);
        acc = fmaf(xb.w, Wp[(k + 7) * FO + lane], acc);
    }
    part[rs][kh][lane] = acc;
    __syncthreads();
    if (threadIdx.x < 128) {
        const int r2 = threadIdx.x >> 6;
        const int l2 = threadIdx.x & 63;
        h[((size_t)blockIdx.x * 2 + r2) * FO + l2] = part[r2][0][l2] + part[r2][1][l2];
    }
}

// ---------------- K1b: hbT_hi/lo[f][j] = bf16 split of h[j][f] (proven) ----------------
__global__ __launch_bounds__(256) void gat_tr(const float* __restrict__ h,
                                              unsigned short* __restrict__ hbT_hi,
                                              unsigned short* __restrict__ hbT_lo) {
    __shared__ float t_s[64 * 68];
    const int tid = threadIdx.x;
    const int j0 = blockIdx.x * 64;       // grid 32
    for (int g4 = tid; g4 < 1024; g4 += 256) {
        float4 v = *(const float4*)(h + (size_t)j0 * FO + (size_t)g4 * 4);
        *(float4*)&t_s[(g4 >> 4) * 68 + (g4 & 15) * 4] = v;
    }
    __syncthreads();
    const int f = tid >> 2, q = tid & 3;
    unsigned* dh = (unsigned*)&hbT_hi[(size_t)f * Nn + j0 + q * 16];
    unsigned* dl = (unsigned*)&hbT_lo[(size_t)f * Nn + j0 + q * 16];
#pragma unroll
    for (int u = 0; u < 8; u++) {
        float x0 = t_s[(q * 16 + 2 * u) * 68 + f];
        float x1 = t_s[(q * 16 + 2 * u + 1) * 68 + f];
        unsigned h0 = rne_bf16(x0), h1 = rne_bf16(x1);
        dh[u] = h0 | (h1 << 16);
        float r0 = x0 - bf16_f32(h0), r1 = x1 - bf16_f32(h1);
        dl[u] = rne_bf16(r0) | (rne_bf16(r1) << 16);
    }
}

// ---------------- K2: deterministic fused attention, conflict-free, occupancy 3/CU ----------------
// Grid = 128 i-tiles x njt j-segments. Block 256 thr = 4 waves, 16 i-rows, chunk = 128 j.
// e-phase: lane (ig=tid>>7 wave-uniform, jg=tid&127) tile = 8i x 1j. hj from LDS stride-68
// (consecutive lanes = consecutive rows -> inherent-minimum bank pattern, no conflicts);
// hi & a are wave-uniform scalar loads (SMEM pipe, free). PV: split hi/lo bf16, 3 MFMA/k.
// No atomics; opart/lpart block-exclusive -> bit-reproducible.
__global__ __launch_bounds__(256, 3) void gat_attn8(const float* __restrict__ h,
                                                    const int* __restrict__ adj,
                                                    const float* __restrict__ a,
                                                    const unsigned short* __restrict__ hbT_hi,
                                                    const unsigned short* __restrict__ hbT_lo,
                                                    float* __restrict__ opart,
                                                    float* __restrict__ lpart,
                                                    int njt_log2) {
    __shared__ float hj_s[CHK * 68];             // 34.8 KB (reused as epilogue scratch)
    __shared__ unsigned short Ph_s[16 * 136];    // 4.35 KB, stride 136 u16 = 68 words (≡4 mod 32)
    __shared__ unsigned short Pl_s[16 * 136];

    const int tid = threadIdx.x;
    const int njt = 1 << njt_log2;
    const int jseg = Nn >> njt_log2;
    const int it = blockIdx.x >> njt_log2;
    const int jt = blockIdx.x & (njt - 1);
    const int ib = it * 16;
    const int jb = jt * jseg;
    const int ig = __builtin_amdgcn_readfirstlane(tid >> 7);  // wave-uniform i-group
    const int jg = tid & 127;
    const int lane = tid & 63;
    const int w = tid >> 6;
    const int m = lane & 15;
    const int g = lane >> 4;

    float ls[8] = {0.f, 0.f, 0.f, 0.f, 0.f, 0.f, 0.f, 0.f};
    f32x4 acc = {0.f, 0.f, 0.f, 0.f};
    const float* hi_base = h + (size_t)(ib + ig * 8) * FO;    // uniform

    for (int jc = 0; jc < jseg; jc += CHK) {
        __syncthreads();    // prev chunk's MFMA done with Ph/Pl; hj_s free
        const float* hsrc = h + (size_t)(jb + jc) * FO;
#pragma unroll
        for (int u = 0; u < 8; u++) {
            const int g4 = u * 256 + tid;                 // 2048 float4s
            *(float4*)&hj_s[(g4 >> 4) * 68 + (g4 & 15) * 4] =
                *(const float4*)(hsrc + (size_t)g4 * 4);
        }
        __syncthreads();

        // adjacency: lane's 8 i-rows, single j (coalesced along jg)
        int amv[8];
        const int* adjp = adj + (size_t)(ib + ig * 8) * Nn + (jb + jc + jg);
#pragma unroll
        for (int ii = 0; ii < 8; ii++) amv[ii] = adjp[(size_t)ii * Nn];

        // ---- e-phase: e[ii] = sum_f a_f |hi[ii][f] - hj[f]| ----
        float e[8];
#pragma unroll
        for (int ii = 0; ii < 8; ii++) e[ii] = 0.f;

#pragma unroll 4
        for (int fq = 0; fq < 16; fq++) {
            const int f = fq * 4;
            const float4 hj = *(const float4*)&hj_s[jg * 68 + f];  // banks 4*jg+f: min-aliasing
            const float4 av = *(const float4*)(a + f);             // uniform -> s_load
#pragma unroll
            for (int ii = 0; ii < 8; ii++) {
                const float4 hi = *(const float4*)(hi_base + ii * FO + f);  // uniform -> s_load
                e[ii] = fmaf(fabsf(hi.x - hj.x), av.x, e[ii]);
                e[ii] = fmaf(fabsf(hi.y - hj.y), av.y, e[ii]);
                e[ii] = fmaf(fabsf(hi.z - hj.z), av.z, e[ii]);
                e[ii] = fmaf(fabsf(hi.w - hj.w), av.w, e[ii]);
            }
        }

        // ---- p = adj ? exp(relu(e)-SHIFT) : 0 (shift-invariant, exact); split bf16 ----
#pragma unroll
        for (int ii = 0; ii < 8; ii++) {
            const float p = (amv[ii] > 0) ? __expf(fmaxf(e[ii], 0.f) - SHIFT) : 0.f;
            ls[ii] += p;
            const unsigned ph = rne_bf16(p);
            const float r = p - bf16_f32(ph);
            Ph_s[(ig * 8 + ii) * 136 + jg] = (unsigned short)ph;
            Pl_s[(ig * 8 + ii) * 136 + jg] = (unsigned short)rne_bf16(r);
        }
        __syncthreads();    // P complete

        // ---- MFMA: wave w owns f-tile w*16..+16, C-resident across chunks ----
        const size_t bbase = (size_t)(w * 16 + m) * Nn + (jb + jc);
#pragma unroll
        for (int ks = 0; ks < 4; ks++) {
            const bf16x8 af = *(const bf16x8*)&Ph_s[m * 136 + ks * 32 + g * 8];
            const bf16x8 al = *(const bf16x8*)&Pl_s[m * 136 + ks * 32 + g * 8];
            const bf16x8 bh = *(const bf16x8*)&hbT_hi[bbase + ks * 32 + g * 8];
            const bf16x8 bl = *(const bf16x8*)&hbT_lo[bbase + ks * 32 + g * 8];
            acc = __builtin_amdgcn_mfma_f32_16x16x32_bf16(af, bh, acc, 0, 0, 0);
            acc = __builtin_amdgcn_mfma_f32_16x16x32_bf16(af, bl, acc, 0, 0, 0);
            acc = __builtin_amdgcn_mfma_f32_16x16x32_bf16(al, bh, acc, 0, 0, 0);
        }
    }

    // ---- epilogue: l-reduction via LDS (reuse hj_s), exclusive writes ----
    __syncthreads();
    float* red = hj_s;
#pragma unroll
    for (int ii = 0; ii < 8; ii++) red[(ig * 8 + ii) * 132 + jg] = ls[ii];
    __syncthreads();
    if (tid < 16) {
        float l = 0.f;
        for (int c2 = 0; c2 < 128; c2++) l += red[tid * 132 + c2];
        lpart[(size_t)jt * Nn + ib + tid] = l;
    }
    // C/D layout: col = lane&15 = f-within-tile, row = g*4+r = i-within-tile (r7-proven)
#pragma unroll
    for (int r = 0; r < 4; r++)
        opart[((size_t)jt * Nn + ib + g * 4 + r) * FO + w * 16 + m] = acc[r];
}

// ---------------- K3: fixed-order merge + normalize + relu ----------------
__global__ __launch_bounds__(256) void gat_merge(const float* __restrict__ opart,
                                                 const float* __restrict__ lpart,
                                                 float* __restrict__ out, int njt) {
    const int t = blockIdx.x * 256 + threadIdx.x;   // grid 512 -> 131072
    const int i = t >> 6;
    float o = 0.f, l = 0.f;
    for (int s = 0; s < njt; s++) {
        o += opart[(size_t)s * Nn * FO + t];
        l += lpart[(size_t)s * Nn + i];
    }
    out[t] = fmaxf(o / l, 0.f);
}

extern "C" void kernel_launch(void* const* d_in, const int* in_sizes, int n_in,
                              void* d_out, int out_size, void* d_ws, size_t ws_size,
                              hipStream_t stream) {
    const float* x   = (const float*)d_in[0];
    const int*   adj = (const int*)d_in[1];
    const float* W   = (const float*)d_in[2];
    const float* a   = (const float*)d_in[3];
    float* out = (float*)d_out;

    // ws-adaptive j-split (deterministic given ws_size -> graph-safe):
    // need(njt) = 1 MB (h + hbT hi/lo) + njt * 532480 B (opart + lpart slices)
    int njt_log2 = 1;                                          // njt=2: 2.11 MB (r2-proven env.)
    if (ws_size >= (size_t)1048576 + 8u * 532480u + 65536u) njt_log2 = 3;        // 5.37 MB
    else if (ws_size >= (size_t)1048576 + 4u * 532480u + 65536u) njt_log2 = 2;   // 3.25 MB
    const int njt = 1 << njt_log2;

    float* h     = (float*)d_ws;                        // 131072 f32
    float* opart = h + (size_t)Nn * FO;                 // njt*131072 f32
    float* lpart = opart + (size_t)njt * Nn * FO;       // njt*2048 f32
    unsigned short* hbT_hi = (unsigned short*)(lpart + (size_t)njt * Nn);  // 256 KB
    unsigned short* hbT_lo = hbT_hi + (size_t)FO * Nn;                     // 256 KB

    gat_xw<<<dim3(1024), dim3(256), 0, stream>>>(x, W, h);
    gat_tr<<<dim3(32), dim3(256), 0, stream>>>(h, hbT_hi, hbT_lo);
    gat_attn8<<<dim3(128 * njt), dim3(256), 0, stream>>>(h, adj, a, hbT_hi, hbT_lo,
                                                         opart, lpart, njt_log2);
    gat_merge<<<dim3(512), dim3(256), 0, stream>>>(opart, lpart, out, njt);
}